// Round 3
// baseline (669.502 us; speedup 1.0000x reference)
//
#include <hip/hip_runtime.h>
#include <hip/hip_bf16.h>

#define BATCH 1024
#define SEQ   256
#define CEMB  384
#define HD    64
#define LDQ   72      // padded row stride for shQ/shK/shX (bf16 elems)
#define LDV   264     // padded row stride for shVT
#define LDP   40      // per-wave P staging stride (80 B rows, 16B aligned)

#define SCALE 0.051031036307982884f   // 384^-0.5 (n_embed, not head_size)
#define LOG2E 1.4426950408889634f

typedef __bf16 bf16x8 __attribute__((ext_vector_type(8)));
typedef float  f32x4  __attribute__((ext_vector_type(4)));

// Repack fp32 Wq,Wk,Wv ([384 in][64 out] row-major) into bf16 Wt[3][64][384]
// (out-major) so MFMA B-fragments (n fixed, 8 consecutive k) are contiguous.
__global__ void repack_w_kernel(const float* __restrict__ Wq,
                                const float* __restrict__ Wk,
                                const float* __restrict__ Wv,
                                __bf16* __restrict__ Wt) {
    int idx = blockIdx.x * blockDim.x + threadIdx.x;
    if (idx >= 3 * HD * CEMB) return;
    int p   = idx / (HD * CEMB);
    int rem = idx - p * (HD * CEMB);
    int n   = rem / CEMB;
    int k   = rem - n * CEMB;
    const float* W = (p == 0) ? Wq : (p == 1) ? Wk : Wv;
    Wt[idx] = (__bf16)W[k * HD + n];
}

__launch_bounds__(512, 2)
__global__ void head_kernel(const float* __restrict__ x,
                            const __bf16* __restrict__ Wt,
                            float* __restrict__ out) {
    __shared__ __align__(16) __bf16 shQ[SEQ][LDQ];   // 36 KB  q[t][h]
    __shared__ __align__(16) __bf16 shK[SEQ][LDQ];   // 36 KB  k[s][h]
    __shared__ __align__(16) __bf16 shVT[HD][LDV];   // 33.8KB v^T[h][s]
    __shared__ __align__(16) __bf16 shX[SEQ][LDQ];   // 36 KB  x chunk (bf16); reused as P staging

    const int b    = blockIdx.x;
    const int tid  = threadIdx.x;
    const int wave = tid >> 6;     // 0..7
    const int lane = tid & 63;
    const int q4   = lane >> 4;    // 0..3
    const int l15  = lane & 15;    // 0..15

    const f32x4 fzero = {0.f, 0.f, 0.f, 0.f};

    // =========== Phase 1: q,k,v = x_b @ {Wq,Wk,Wv}  (M=256,N=64,K=384) ===========
    f32x4 accP[3][2][4];
    #pragma unroll
    for (int p = 0; p < 3; ++p)
        #pragma unroll
        for (int mi = 0; mi < 2; ++mi)
            #pragma unroll
            for (int jn = 0; jn < 4; ++jn) accP[p][mi][jn] = fzero;

    const size_t xbase = (size_t)b * SEQ * CEMB;
    for (int kc = 0; kc < 6; ++kc) {             // K chunks of 64 cols
        // stage x[b][0:256][kc*64 .. +64) -> bf16 shX
        #pragma unroll
        for (int pass = 0; pass < 4; ++pass) {
            int t   = pass * 64 + (tid >> 3);
            int seg = (tid & 7) * 8;
            f32x4 lo = *(const f32x4*)(x + xbase + (size_t)t * CEMB + kc * 64 + seg);
            f32x4 hi = *(const f32x4*)(x + xbase + (size_t)t * CEMB + kc * 64 + seg + 4);
            bf16x8 val;
            #pragma unroll
            for (int i = 0; i < 4; ++i) { val[i] = (__bf16)lo[i]; val[i + 4] = (__bf16)hi[i]; }
            *(bf16x8*)&shX[t][seg] = val;
        }
        __syncthreads();
        #pragma unroll
        for (int ks = 0; ks < 2; ++ks) {         // two K=32 steps per chunk
            bf16x8 afrag[2];
            #pragma unroll
            for (int mi = 0; mi < 2; ++mi)
                afrag[mi] = *(const bf16x8*)&shX[wave * 32 + mi * 16 + l15][ks * 32 + q4 * 8];
            #pragma unroll
            for (int p = 0; p < 3; ++p) {
                #pragma unroll
                for (int jn = 0; jn < 4; ++jn) {
                    bf16x8 bfrag = *(const bf16x8*)(Wt + (size_t)(p * HD + jn * 16 + l15) * CEMB
                                                      + kc * 64 + ks * 32 + q4 * 8);
                    #pragma unroll
                    for (int mi = 0; mi < 2; ++mi)
                        accP[p][mi][jn] = __builtin_amdgcn_mfma_f32_16x16x32_bf16(
                            afrag[mi], bfrag, accP[p][mi][jn], 0, 0, 0);
                }
            }
        }
        __syncthreads();
    }

    // write q,k (row-major padded) and v transposed to LDS (bf16).
    // C/D layout: row = q4*4 + r, col = l15 (within 16x16 tile)
    #pragma unroll
    for (int mi = 0; mi < 2; ++mi)
        #pragma unroll
        for (int jn = 0; jn < 4; ++jn)
            #pragma unroll
            for (int r = 0; r < 4; ++r) {
                int t = wave * 32 + mi * 16 + q4 * 4 + r;
                int h = jn * 16 + l15;
                shQ[t][h]  = (__bf16)accP[0][mi][jn][r];
                shK[t][h]  = (__bf16)accP[1][mi][jn][r];
                shVT[h][t] = (__bf16)accP[2][mi][jn][r];
            }
    __syncthreads();

    // =========== Phase 2: causal attention; wave handles t-tiles {wave, 15-wave} ===========
    __bf16* stg = &shX[0][0] + wave * (16 * LDP);   // per-wave 16 x LDP staging

    #pragma unroll
    for (int m = 0; m < 2; ++m) {
        const int mt = m ? (15 - wave) : wave;      // strip's t-tile index

        // ---- S = q_tile @ k^T (scaled), causal ----
        f32x4 accS[16];
        #pragma unroll
        for (int j = 0; j < 16; ++j) accS[j] = fzero;

        bf16x8 aq[2];
        #pragma unroll
        for (int ks = 0; ks < 2; ++ks)
            aq[ks] = *(const bf16x8*)&shQ[mt * 16 + l15][ks * 32 + q4 * 8];

        #pragma unroll
        for (int j = 0; j < 16; ++j) {
            if (j <= mt) {
                bf16x8 bk0 = *(const bf16x8*)&shK[j * 16 + l15][q4 * 8];
                bf16x8 bk1 = *(const bf16x8*)&shK[j * 16 + l15][32 + q4 * 8];
                accS[j] = __builtin_amdgcn_mfma_f32_16x16x32_bf16(aq[0], bk0, accS[j], 0, 0, 0);
                accS[j] = __builtin_amdgcn_mfma_f32_16x16x32_bf16(aq[1], bk1, accS[j], 0, 0, 0);
            }
        }

        // ---- softmax per row (row group = 16 lanes sharing q4, varying l15) ----
        float mx[4] = {-1e30f, -1e30f, -1e30f, -1e30f};
        #pragma unroll
        for (int j = 0; j < 16; ++j) {
            if (j > mt) continue;
            #pragma unroll
            for (int r = 0; r < 4; ++r) {
                float sv = accS[j][r] * SCALE;
                bool valid = (j < mt) || (l15 <= q4 * 4 + r);
                sv = valid ? sv : -1e30f;
                accS[j][r] = sv;
                mx[r] = fmaxf(mx[r], sv);
            }
        }
        #pragma unroll
        for (int off = 1; off < 16; off <<= 1)
            #pragma unroll
            for (int r = 0; r < 4; ++r)
                mx[r] = fmaxf(mx[r], __shfl_xor(mx[r], off, 64));

        float sm[4] = {0.f, 0.f, 0.f, 0.f};
        #pragma unroll
        for (int j = 0; j < 16; ++j) {
            if (j > mt) continue;
            #pragma unroll
            for (int r = 0; r < 4; ++r) {
                float pv = exp2f((accS[j][r] - mx[r]) * LOG2E);
                accS[j][r] = pv;
                sm[r] += pv;
            }
        }
        #pragma unroll
        for (int off = 1; off < 16; off <<= 1)
            #pragma unroll
            for (int r = 0; r < 4; ++r)
                sm[r] += __shfl_xor(sm[r], off, 64);
        float rinv[4];
        #pragma unroll
        for (int r = 0; r < 4; ++r) rinv[r] = 1.0f / sm[r];

        // ---- O = P @ v  (P: C-layout -> A-layout via per-wave LDS staging) ----
        f32x4 accO[4] = {fzero, fzero, fzero, fzero};
        const int ksmax = (mt * 16 + 15) >> 5;
        #pragma unroll
        for (int ks = 0; ks < 8; ++ks) {
            if (ks > ksmax) continue;
            __asm__ __volatile__("" ::: "memory");
            #pragma unroll
            for (int jj = 0; jj < 2; ++jj) {
                int j = 2 * ks + jj;
                #pragma unroll
                for (int r = 0; r < 4; ++r) {
                    float pv = (j <= mt) ? (float)accS[j][r] : 0.0f;
                    stg[(q4 * 4 + r) * LDP + jj * 16 + l15] = (__bf16)pv;
                }
            }
            // wave-internal LDS RAW: writes complete + no compiler reorder
            __asm__ __volatile__("s_waitcnt lgkmcnt(0)" ::: "memory");
            bf16x8 ap = *(const bf16x8*)(stg + l15 * LDP + q4 * 8);
            #pragma unroll
            for (int hj = 0; hj < 4; ++hj) {
                bf16x8 bv = *(const bf16x8*)&shVT[hj * 16 + l15][ks * 32 + q4 * 8];
                accO[hj] = __builtin_amdgcn_mfma_f32_16x16x32_bf16(ap, bv, accO[hj], 0, 0, 0);
            }
        }

        // ---- epilogue: out[b][t][h] = accO / l  (fp32 out) ----
        #pragma unroll
        for (int hj = 0; hj < 4; ++hj)
            #pragma unroll
            for (int r = 0; r < 4; ++r) {
                int t = mt * 16 + q4 * 4 + r;
                int h = hj * 16 + l15;
                out[((size_t)b * SEQ + t) * HD + h] = accO[hj][r] * rinv[r];
            }
    }
}

extern "C" void kernel_launch(void* const* d_in, const int* in_sizes, int n_in,
                              void* d_out, int out_size, void* d_ws, size_t ws_size,
                              hipStream_t stream) {
    const float* x  = (const float*)d_in[0];
    const float* Wq = (const float*)d_in[1];
    const float* Wk = (const float*)d_in[2];
    const float* Wv = (const float*)d_in[3];
    __bf16* Wt = (__bf16*)d_ws;     // 3*64*384*2 = 147456 B
    float* out = (float*)d_out;

    repack_w_kernel<<<(3 * HD * CEMB + 255) / 256, 256, 0, stream>>>(Wq, Wk, Wv, Wt);
    head_kernel<<<BATCH, 512, 0, stream>>>(x, Wt, out);
}